// Round 5
// baseline (459.600 us; speedup 1.0000x reference)
//
#include <hip/hip_runtime.h>

#define EPS 1e-3f

typedef __attribute__((ext_vector_type(8))) short bf8_t;   // 8 bf16 (4 VGPRs)
typedef __attribute__((ext_vector_type(4))) float f32x4;   // MFMA acc

static __device__ __forceinline__ unsigned f2bf_pack(float a, float b) {
  union { float f; unsigned u; } ca, cb;
  ca.f = a; cb.f = b;
  unsigned ra = (ca.u + 0x7FFFu + ((ca.u >> 16) & 1u)) >> 16;
  unsigned rb = (cb.u + 0x7FFFu + ((cb.u >> 16) & 1u)) >> 16;
  return ra | (rb << 16);
}
static __device__ __forceinline__ unsigned short f2bf1(float x) {
  union { float f; unsigned u; } c; c.f = x;
  return (unsigned short)((c.u + 0x7FFFu + ((c.u >> 16) & 1u)) >> 16);
}
static __device__ __forceinline__ float bf2f(unsigned bits16) {
  union { unsigned u; float f; } c;
  c.u = bits16 << 16;
  return c.f;
}

// ===========================================================================
// FULL (MFMA + bf16) PATH
// ===========================================================================

// feats (f1|f2) fp32 -> fbuf bf16, (N+1) rows x 64, row N = zeros
__global__ __launch_bounds__(256) void to_bf16(
    const float* __restrict__ f1, const float* __restrict__ f2,
    unsigned short* __restrict__ fbuf, int N1, int N) {
  int idx = blockIdx.x * 256 + threadIdx.x;  // (N+1)*8 segs of 8 elems
  if (idx >= (N + 1) * 8) return;
  int row = idx >> 3, seg = idx & 7;
  uint4 o = make_uint4(0, 0, 0, 0);
  if (row < N) {
    const float* src = (row < N1) ? (f1 + (size_t)row * 64)
                                  : (f2 + (size_t)(row - N1) * 64);
    float4 v0 = *(const float4*)(src + seg * 8);
    float4 v1 = *(const float4*)(src + seg * 8 + 4);
    o.x = f2bf_pack(v0.x, v0.y); o.y = f2bf_pack(v0.z, v0.w);
    o.z = f2bf_pack(v1.x, v1.y); o.w = f2bf_pack(v1.z, v1.w);
  }
  *(uint4*)(fbuf + (size_t)idx * 8) = o;
}

// W[27][64][128] fp32 -> Wb[27][128][64] bf16 (transposed, k contiguous)
__global__ __launch_bounds__(256) void wconv(
    const float* __restrict__ W, unsigned short* __restrict__ Wb) {
  int idx = blockIdx.x * 256 + threadIdx.x;  // 27*128*64 = 221184 exact
  int k = idx & 63, n = (idx >> 6) & 127, t = idx >> 13;
  Wb[idx] = f2bf1(W[((size_t)t * 64 + k) * 128 + n]);
}

// inverse rulebook: R[s*26+i] = i*pm+p (msgbuf row). R pre-memset to -1.
__global__ __launch_bounds__(256) void scatter_R(
    const int* __restrict__ S, int* __restrict__ R, int N, int pm) {
  const int p = blockIdx.x * 256 + threadIdx.x;
  const int i = blockIdx.y;
  if (p >= pm) return;
  const int idx = i * pm + p;
  const int s = S[idx];
  if (s < N) R[(size_t)s * 26 + i] = idx;
}

// center tap: outb[n][col] = bf16( feats[n].W13[:,col] + bias[col] )
// 128x128 tile, 4 waves, 16x16x32 bf16 MFMA. A staged in LDS frag-ordered;
// B frags read straight from global Wb (L2-resident, 16 KB).
__global__ __launch_bounds__(256) void center_mfma(
    const unsigned short* __restrict__ fbuf,
    const unsigned short* __restrict__ Wb13,
    const float* __restrict__ bias,
    unsigned short* __restrict__ outb, int N) {
  __shared__ unsigned short A[128 * 64];  // [rt(8)][c(2)][lane(64)][8]
  const int tid = threadIdx.x;
  const int row0 = blockIdx.x * 128;

#pragma unroll
  for (int it = 0; it < 4; ++it) {
    int flat = it * 256 + tid;
    int r = flat >> 3, qs = flat & 7;
    int g = row0 + r; if (g >= N) g = N;  // row N is zeros
    uint4 v = *(const uint4*)(fbuf + (size_t)g * 64 + qs * 8);
    int rt = r >> 4, m = r & 15, c = qs >> 2, qq = qs & 3;
    *(uint4*)(A + ((rt * 2 + c) * 64 + qq * 16 + m) * 8) = v;
  }
  __syncthreads();

  const int wave = tid >> 6, lane = tid & 63;
  const int ncol = lane & 15, q2 = lane >> 4;
  bf8_t Bf[2][2];
  float bs[2];
#pragma unroll
  for (int ct = 0; ct < 2; ++ct) {
    int col = wave * 32 + ct * 16 + ncol;
    bs[ct] = bias[col];
#pragma unroll
    for (int c = 0; c < 2; ++c)
      Bf[ct][c] = *(const bf8_t*)(Wb13 + (size_t)col * 64 + c * 32 + q2 * 8);
  }
  f32x4 acc[8][2];
#pragma unroll
  for (int rt = 0; rt < 8; ++rt)
#pragma unroll
    for (int ct = 0; ct < 2; ++ct) acc[rt][ct] = (f32x4){0.f, 0.f, 0.f, 0.f};

#pragma unroll
  for (int rt = 0; rt < 8; ++rt) {
    bf8_t a0 = *(const bf8_t*)(A + ((rt * 2 + 0) * 64 + lane) * 8);
    bf8_t a1 = *(const bf8_t*)(A + ((rt * 2 + 1) * 64 + lane) * 8);
#pragma unroll
    for (int ct = 0; ct < 2; ++ct) {
      acc[rt][ct] = __builtin_amdgcn_mfma_f32_16x16x32_bf16(a0, Bf[ct][0], acc[rt][ct], 0, 0, 0);
      acc[rt][ct] = __builtin_amdgcn_mfma_f32_16x16x32_bf16(a1, Bf[ct][1], acc[rt][ct], 0, 0, 0);
    }
  }

#pragma unroll
  for (int rt = 0; rt < 8; ++rt)
#pragma unroll
    for (int ct = 0; ct < 2; ++ct) {
      int col = wave * 32 + ct * 16 + ncol;
#pragma unroll
      for (int e = 0; e < 4; ++e) {
        int row = row0 + rt * 16 + q2 * 4 + e;
        if (row < N)
          outb[(size_t)row * 128 + col] = f2bf1(acc[rt][ct][e] + bs[ct]);
      }
    }
}

// 26 neighbor taps: msgbuf[tap*pm+p] = bf16( feats[G[tap][p]] . W_k )
__global__ __launch_bounds__(256) void msg_mfma(
    const unsigned short* __restrict__ fbuf,
    const unsigned short* __restrict__ Wb,
    const int* __restrict__ G,
    unsigned short* __restrict__ msgbuf, int N, int pm) {
  const int tap = blockIdx.y;                 // tap index (0..25)
  const int ktap = tap + (tap >= 13 ? 1 : 0);
  const unsigned short* Wt = Wb + (size_t)ktap * 128 * 64;
  const int* Gi = G + (size_t)tap * pm;
  const int p0 = blockIdx.x * 128;
  if (Gi[p0] >= N) return;  // fully-padded tail block (padding G == N)

  __shared__ unsigned short A[128 * 64];
  __shared__ int g_lds[128];
  const int tid = threadIdx.x;
  if (tid < 128) {
    int p = p0 + tid;
    g_lds[tid] = (p < pm) ? Gi[p] : N;
  }
  __syncthreads();

#pragma unroll
  for (int it = 0; it < 4; ++it) {
    int flat = it * 256 + tid;
    int r = flat >> 3, qs = flat & 7;
    int g = g_lds[r];
    uint4 v = *(const uint4*)(fbuf + (size_t)g * 64 + qs * 8);
    int rt = r >> 4, m = r & 15, c = qs >> 2, qq = qs & 3;
    *(uint4*)(A + ((rt * 2 + c) * 64 + qq * 16 + m) * 8) = v;
  }
  __syncthreads();

  const int wave = tid >> 6, lane = tid & 63;
  const int ncol = lane & 15, q2 = lane >> 4;
  bf8_t Bf[2][2];
#pragma unroll
  for (int ct = 0; ct < 2; ++ct) {
    int col = wave * 32 + ct * 16 + ncol;
#pragma unroll
    for (int c = 0; c < 2; ++c)
      Bf[ct][c] = *(const bf8_t*)(Wt + (size_t)col * 64 + c * 32 + q2 * 8);
  }
  f32x4 acc[8][2];
#pragma unroll
  for (int rt = 0; rt < 8; ++rt)
#pragma unroll
    for (int ct = 0; ct < 2; ++ct) acc[rt][ct] = (f32x4){0.f, 0.f, 0.f, 0.f};

#pragma unroll
  for (int rt = 0; rt < 8; ++rt) {
    bf8_t a0 = *(const bf8_t*)(A + ((rt * 2 + 0) * 64 + lane) * 8);
    bf8_t a1 = *(const bf8_t*)(A + ((rt * 2 + 1) * 64 + lane) * 8);
#pragma unroll
    for (int ct = 0; ct < 2; ++ct) {
      acc[rt][ct] = __builtin_amdgcn_mfma_f32_16x16x32_bf16(a0, Bf[ct][0], acc[rt][ct], 0, 0, 0);
      acc[rt][ct] = __builtin_amdgcn_mfma_f32_16x16x32_bf16(a1, Bf[ct][1], acc[rt][ct], 0, 0, 0);
    }
  }

#pragma unroll
  for (int rt = 0; rt < 8; ++rt)
#pragma unroll
    for (int ct = 0; ct < 2; ++ct) {
      int col = wave * 32 + ct * 16 + ncol;
#pragma unroll
      for (int e = 0; e < 4; ++e) {
        int p = p0 + rt * 16 + q2 * 4 + e;
        if (p < pm)
          msgbuf[((size_t)tap * pm + p) * 128 + col] = f2bf1(acc[rt][ct][e]);
      }
    }
}

// combine: outb[j] += sum of its bf16 messages (via R); per-channel stats.
__global__ __launch_bounds__(256) void combine_b(
    unsigned short* __restrict__ outb, const int* __restrict__ R,
    const unsigned short* __restrict__ msgbuf, float* __restrict__ ws,
    int N) {
  const int tid = threadIdx.x;
  const int grp = tid >> 5, l = tid & 31;
  const int base = tid & 32;
  float4 s = make_float4(0.f, 0.f, 0.f, 0.f);
  float4 q = make_float4(0.f, 0.f, 0.f, 0.f);

  for (int j = blockIdx.x * 8 + grp; j < N; j += gridDim.x * 8) {
    uint2 ov = ((const uint2*)(outb + (size_t)j * 128))[l];
    float4 v;
    v.x = bf2f(ov.x & 0xffffu); v.y = bf2f(ov.x >> 16);
    v.z = bf2f(ov.y & 0xffffu); v.w = bf2f(ov.y >> 16);
    int r = (l < 26) ? R[(size_t)j * 26 + l] : -1;
    unsigned long long bal = __ballot(r >= 0);
    unsigned mym = (unsigned)((bal >> base) & 0x3FFFFFFull);
    const bool any = (mym != 0);
    while (mym) {
      int b = __builtin_ctz(mym);
      mym &= mym - 1;
      int ptr = __shfl(r, base + b, 64);
      uint2 mv = ((const uint2*)(msgbuf + (size_t)ptr * 128))[l];
      v.x += bf2f(mv.x & 0xffffu); v.y += bf2f(mv.x >> 16);
      v.z += bf2f(mv.y & 0xffffu); v.w += bf2f(mv.y >> 16);
    }
    if (any) {
      uint2 pk;
      pk.x = f2bf_pack(v.x, v.y); pk.y = f2bf_pack(v.z, v.w);
      ((uint2*)(outb + (size_t)j * 128))[l] = pk;
    }
    s.x += v.x; s.y += v.y; s.z += v.z; s.w += v.w;
    q.x += v.x * v.x; q.y += v.y * v.y; q.z += v.z * v.z; q.w += v.w * v.w;
  }

  __shared__ float red[8 * 32 * 8];
  float* my = red + (grp * 32 + l) * 8;
  my[0] = s.x; my[1] = s.y; my[2] = s.z; my[3] = s.w;
  my[4] = q.x; my[5] = q.y; my[6] = q.z; my[7] = q.w;
  __syncthreads();
  {
    int c4 = tid & 31, jj = tid >> 5;
    float v = 0.f;
#pragma unroll
    for (int g = 0; g < 8; ++g) v += red[(g * 32 + c4) * 8 + jj];
    int col = c4 * 4 + (jj & 3);
    unsafeAtomicAdd(&ws[col + (jj >> 2) * 128], v);
  }
}

// normalize bf16 pre-norm buffer -> fp32 final out
__global__ __launch_bounds__(256) void norm_b(
    const unsigned short* __restrict__ outb, float* __restrict__ out,
    const float* __restrict__ ws, const float* __restrict__ gamma,
    const float* __restrict__ beta, int total8, float invN) {
  const int tid0 = blockIdx.x * 256 + threadIdx.x;
  const int c0 = (tid0 & 15) * 8;
  float sc[8], sh[8];
#pragma unroll
  for (int k = 0; k < 8; ++k) {
    float m = ws[c0 + k] * invN;
    float var = ws[128 + c0 + k] * invN - m * m;
    sc[k] = gamma[c0 + k] * rsqrtf(var + EPS);
    sh[k] = beta[c0 + k] - m * sc[k];
  }
  for (int idx = tid0; idx < total8; idx += gridDim.x * 256) {
    uint4 v = *(const uint4*)(outb + (size_t)idx * 8);
    float f0 = bf2f(v.x & 0xffffu), f1 = bf2f(v.x >> 16);
    float f2 = bf2f(v.y & 0xffffu), f3 = bf2f(v.y >> 16);
    float f4 = bf2f(v.z & 0xffffu), f5 = bf2f(v.z >> 16);
    float f6 = bf2f(v.w & 0xffffu), f7 = bf2f(v.w >> 16);
    float4 o0, o1;
    o0.x = fmaxf(f0 * sc[0] + sh[0], 0.f);
    o0.y = fmaxf(f1 * sc[1] + sh[1], 0.f);
    o0.z = fmaxf(f2 * sc[2] + sh[2], 0.f);
    o0.w = fmaxf(f3 * sc[3] + sh[3], 0.f);
    o1.x = fmaxf(f4 * sc[4] + sh[4], 0.f);
    o1.y = fmaxf(f5 * sc[5] + sh[5], 0.f);
    o1.z = fmaxf(f6 * sc[6] + sh[6], 0.f);
    o1.w = fmaxf(f7 * sc[7] + sh[7], 0.f);
    *(float4*)(out + (size_t)idx * 8) = o0;
    *(float4*)(out + (size_t)idx * 8 + 4) = o1;
  }
}

// ===========================================================================
// FALLBACK PATHS (round-2 fp32 pipeline; round-1 atomic pipeline)
// ===========================================================================

__global__ __launch_bounds__(256) void center_gemm(
    const float* __restrict__ f1, const float* __restrict__ f2,
    const float* __restrict__ W, const float* __restrict__ bias,
    float* __restrict__ out, int N, int N1) {
  __shared__ float fLDS[128 * 65];
  __shared__ float wLDS[32 * 128];
  const int tid = threadIdx.x;
  const int tx = tid & 15, ty = tid >> 4;
  const int row0 = blockIdx.x * 128;

  for (int k = 0; k < 8; ++k) {
    int flat4 = tid + k * 256;
    int row = flat4 >> 4, c4 = flat4 & 15;
    int grow = row0 + row;
    float4 v = make_float4(0.f, 0.f, 0.f, 0.f);
    if (grow < N) {
      const float* src = (grow < N1) ? (f1 + (size_t)grow * 64)
                                     : (f2 + (size_t)(grow - N1) * 64);
      v = *(const float4*)(src + c4 * 4);
    }
    int l = row * 65 + c4 * 4;
    fLDS[l + 0] = v.x; fLDS[l + 1] = v.y; fLDS[l + 2] = v.z; fLDS[l + 3] = v.w;
  }
  float acc[8][8];
#pragma unroll
  for (int r = 0; r < 8; ++r)
#pragma unroll
    for (int j = 0; j < 8; ++j) acc[r][j] = 0.f;
  for (int kk = 0; kk < 64; kk += 32) {
    __syncthreads();
    for (int k = 0; k < 4; ++k) {
      int flat4 = tid + k * 256;
      int c = flat4 >> 5, col4 = flat4 & 31;
      float4 v = *(const float4*)(W + (size_t)(kk + c) * 128 + col4 * 4);
      *(float4*)(wLDS + c * 128 + col4 * 4) = v;
    }
    __syncthreads();
#pragma unroll 4
    for (int c = 0; c < 32; ++c) {
      float a[8];
#pragma unroll
      for (int r = 0; r < 8; ++r) a[r] = fLDS[(ty * 8 + r) * 65 + kk + c];
      float4 b0 = *(const float4*)(wLDS + c * 128 + tx * 8);
      float4 b1 = *(const float4*)(wLDS + c * 128 + tx * 8 + 4);
      float b[8] = {b0.x, b0.y, b0.z, b0.w, b1.x, b1.y, b1.z, b1.w};
#pragma unroll
      for (int r = 0; r < 8; ++r)
#pragma unroll
        for (int j = 0; j < 8; ++j) acc[r][j] += a[r] * b[j];
    }
  }
  float4 bi0 = *(const float4*)(bias + tx * 8);
  float4 bi1 = *(const float4*)(bias + tx * 8 + 4);
#pragma unroll
  for (int r = 0; r < 8; ++r) {
    int grow = row0 + ty * 8 + r;
    if (grow < N) {
      float4 o0 = make_float4(acc[r][0] + bi0.x, acc[r][1] + bi0.y,
                              acc[r][2] + bi0.z, acc[r][3] + bi0.w);
      float4 o1 = make_float4(acc[r][4] + bi1.x, acc[r][5] + bi1.y,
                              acc[r][6] + bi1.z, acc[r][7] + bi1.w);
      float* dst = out + (size_t)grow * 128 + tx * 8;
      *(float4*)dst = o0;
      *(float4*)(dst + 4) = o1;
    }
  }
}

__global__ __launch_bounds__(256) void msg_gemm_buf(
    const float* __restrict__ f1, const float* __restrict__ f2,
    const float* __restrict__ W27, const int* __restrict__ G,
    const int* __restrict__ S, unsigned short* __restrict__ msgbuf,
    int N, int N1, int pm) {
  const int i = blockIdx.y;
  const int ktap = i + (i >= 13 ? 1 : 0);
  const float* W = W27 + (size_t)ktap * 64 * 128;
  const int* Gi = G + (size_t)i * pm;
  const int* Si = S + (size_t)i * pm;
  const int p0 = blockIdx.x * 128;
  if (Si[p0] >= N) return;
  __shared__ float fLDS[128 * 65];
  __shared__ float wLDS[32 * 128];
  const int tid = threadIdx.x;
  const int tx = tid & 15, ty = tid >> 4;
  for (int k = 0; k < 8; ++k) {
    int flat4 = tid + k * 256;
    int row = flat4 >> 4, c4 = flat4 & 15;
    int p = p0 + row;
    float4 v = make_float4(0.f, 0.f, 0.f, 0.f);
    if (p < pm) {
      int g = Gi[p];
      if (g < N) {
        const float* src = (g < N1) ? (f1 + (size_t)g * 64)
                                    : (f2 + (size_t)(g - N1) * 64);
        v = *(const float4*)(src + c4 * 4);
      }
    }
    int l = row * 65 + c4 * 4;
    fLDS[l + 0] = v.x; fLDS[l + 1] = v.y; fLDS[l + 2] = v.z; fLDS[l + 3] = v.w;
  }
  float acc[8][8];
#pragma unroll
  for (int r = 0; r < 8; ++r)
#pragma unroll
    for (int j = 0; j < 8; ++j) acc[r][j] = 0.f;
  for (int kk = 0; kk < 64; kk += 32) {
    __syncthreads();
    for (int k = 0; k < 4; ++k) {
      int flat4 = tid + k * 256;
      int c = flat4 >> 5, col4 = flat4 & 31;
      float4 v = *(const float4*)(W + (size_t)(kk + c) * 128 + col4 * 4);
      *(float4*)(wLDS + c * 128 + col4 * 4) = v;
    }
    __syncthreads();
#pragma unroll 4
    for (int c = 0; c < 32; ++c) {
      float a[8];
#pragma unroll
      for (int r = 0; r < 8; ++r) a[r] = fLDS[(ty * 8 + r) * 65 + kk + c];
      float4 b0 = *(const float4*)(wLDS + c * 128 + tx * 8);
      float4 b1 = *(const float4*)(wLDS + c * 128 + tx * 8 + 4);
      float b[8] = {b0.x, b0.y, b0.z, b0.w, b1.x, b1.y, b1.z, b1.w};
#pragma unroll
      for (int r = 0; r < 8; ++r)
#pragma unroll
        for (int j = 0; j < 8; ++j) acc[r][j] += a[r] * b[j];
    }
  }
#pragma unroll
  for (int r = 0; r < 8; ++r) {
    int p = p0 + ty * 8 + r;
    if (p < pm) {
      uint4 pk;
      pk.x = f2bf_pack(acc[r][0], acc[r][1]);
      pk.y = f2bf_pack(acc[r][2], acc[r][3]);
      pk.z = f2bf_pack(acc[r][4], acc[r][5]);
      pk.w = f2bf_pack(acc[r][6], acc[r][7]);
      *(uint4*)(msgbuf + ((size_t)i * pm + p) * 128 + tx * 8) = pk;
    }
  }
}

__global__ __launch_bounds__(256) void msg_gemm(
    const float* __restrict__ f1, const float* __restrict__ f2,
    const float* __restrict__ W27, const int* __restrict__ G,
    const int* __restrict__ S, float* __restrict__ out,
    int N, int N1, int pm) {
  const int i = blockIdx.y;
  const int ktap = i + (i >= 13 ? 1 : 0);
  const float* W = W27 + (size_t)ktap * 64 * 128;
  const int* Gi = G + (size_t)i * pm;
  const int* Si = S + (size_t)i * pm;
  const int p0 = blockIdx.x * 128;
  if (Si[p0] >= N) return;
  __shared__ float fLDS[128 * 65];
  __shared__ float wLDS[32 * 128];
  const int tid = threadIdx.x;
  const int tx = tid & 15, ty = tid >> 4;
  for (int k = 0; k < 8; ++k) {
    int flat4 = tid + k * 256;
    int row = flat4 >> 4, c4 = flat4 & 15;
    int p = p0 + row;
    float4 v = make_float4(0.f, 0.f, 0.f, 0.f);
    if (p < pm) {
      int g = Gi[p];
      if (g < N) {
        const float* src = (g < N1) ? (f1 + (size_t)g * 64)
                                    : (f2 + (size_t)(g - N1) * 64);
        v = *(const float4*)(src + c4 * 4);
      }
    }
    int l = row * 65 + c4 * 4;
    fLDS[l + 0] = v.x; fLDS[l + 1] = v.y; fLDS[l + 2] = v.z; fLDS[l + 3] = v.w;
  }
  float acc[8][8];
#pragma unroll
  for (int r = 0; r < 8; ++r)
#pragma unroll
    for (int j = 0; j < 8; ++j) acc[r][j] = 0.f;
  for (int kk = 0; kk < 64; kk += 32) {
    __syncthreads();
    for (int k = 0; k < 4; ++k) {
      int flat4 = tid + k * 256;
      int c = flat4 >> 5, col4 = flat4 & 31;
      float4 v = *(const float4*)(W + (size_t)(kk + c) * 128 + col4 * 4);
      *(float4*)(wLDS + c * 128 + col4 * 4) = v;
    }
    __syncthreads();
#pragma unroll 4
    for (int c = 0; c < 32; ++c) {
      float a[8];
#pragma unroll
      for (int r = 0; r < 8; ++r) a[r] = fLDS[(ty * 8 + r) * 65 + kk + c];
      float4 b0 = *(const float4*)(wLDS + c * 128 + tx * 8);
      float4 b1 = *(const float4*)(wLDS + c * 128 + tx * 8 + 4);
      float b[8] = {b0.x, b0.y, b0.z, b0.w, b1.x, b1.y, b1.z, b1.w};
#pragma unroll
      for (int r = 0; r < 8; ++r)
#pragma unroll
        for (int j = 0; j < 8; ++j) acc[r][j] += a[r] * b[j];
    }
  }
#pragma unroll
  for (int r = 0; r < 8; ++r) {
    int p = p0 + ty * 8 + r;
    if (p < pm) {
      int s = Si[p];
      if (s < N) {
        float* dst = out + (size_t)s * 128 + tx * 8;
#pragma unroll
        for (int j = 0; j < 8; ++j) unsafeAtomicAdd(dst + j, acc[r][j]);
      }
    }
  }
}

__global__ __launch_bounds__(256) void combine_stats(
    float* __restrict__ out, const int* __restrict__ R,
    const unsigned short* __restrict__ msgbuf, float* __restrict__ ws,
    int N) {
  const int tid = threadIdx.x;
  const int grp = tid >> 5, l = tid & 31;
  const int base = tid & 32;
  float4 s = make_float4(0.f, 0.f, 0.f, 0.f);
  float4 q = make_float4(0.f, 0.f, 0.f, 0.f);
  for (int j = blockIdx.x * 8 + grp; j < N; j += gridDim.x * 8) {
    float4 v = ((const float4*)(out + (size_t)j * 128))[l];
    int r = (l < 26) ? R[(size_t)j * 26 + l] : -1;
    unsigned long long bal = __ballot(r >= 0);
    unsigned mym = (unsigned)((bal >> base) & 0x3FFFFFFull);
    const bool any = (mym != 0);
    while (mym) {
      int b = __builtin_ctz(mym);
      mym &= mym - 1;
      int ptr = __shfl(r, base + b, 64);
      uint2 mv = ((const uint2*)(msgbuf + (size_t)ptr * 128))[l];
      v.x += bf2f(mv.x & 0xffffu);
      v.y += bf2f(mv.x >> 16);
      v.z += bf2f(mv.y & 0xffffu);
      v.w += bf2f(mv.y >> 16);
    }
    if (any) ((float4*)(out + (size_t)j * 128))[l] = v;
    s.x += v.x; s.y += v.y; s.z += v.z; s.w += v.w;
    q.x += v.x * v.x; q.y += v.y * v.y; q.z += v.z * v.z; q.w += v.w * v.w;
  }
  __shared__ float red[8 * 32 * 8];
  float* my = red + (grp * 32 + l) * 8;
  my[0] = s.x; my[1] = s.y; my[2] = s.z; my[3] = s.w;
  my[4] = q.x; my[5] = q.y; my[6] = q.z; my[7] = q.w;
  __syncthreads();
  {
    int c4 = tid & 31, j = tid >> 5;
    float v = 0.f;
#pragma unroll
    for (int g = 0; g < 8; ++g) v += red[(g * 32 + c4) * 8 + j];
    int col = c4 * 4 + (j & 3);
    unsafeAtomicAdd(&ws[col + (j >> 2) * 128], v);
  }
}

__global__ __launch_bounds__(256) void stats_kernel(
    const float* __restrict__ out, float* __restrict__ ws, int total4) {
  const int tid = threadIdx.x;
  float4 s = make_float4(0.f, 0.f, 0.f, 0.f);
  float4 q = make_float4(0.f, 0.f, 0.f, 0.f);
  const float4* o4 = (const float4*)out;
  for (int idx = blockIdx.x * 256 + tid; idx < total4; idx += gridDim.x * 256) {
    float4 v = o4[idx];
    s.x += v.x; s.y += v.y; s.z += v.z; s.w += v.w;
    q.x += v.x * v.x; q.y += v.y * v.y; q.z += v.z * v.z; q.w += v.w * v.w;
  }
  __shared__ float red[8 * 32 * 8];
  const int col4 = tid & 31, grpq = tid >> 5;
  float* my = red + (grpq * 32 + col4) * 8;
  my[0] = s.x; my[1] = s.y; my[2] = s.z; my[3] = s.w;
  my[4] = q.x; my[5] = q.y; my[6] = q.z; my[7] = q.w;
  __syncthreads();
  {
    int c4 = tid & 31, j = tid >> 5;
    float v = 0.f;
#pragma unroll
    for (int g = 0; g < 8; ++g) v += red[(g * 32 + c4) * 8 + j];
    int col = c4 * 4 + (j & 3);
    unsafeAtomicAdd(&ws[col + (j >> 2) * 128], v);
  }
}

__global__ __launch_bounds__(256) void norm_kernel(
    float* __restrict__ out, const float* __restrict__ ws,
    const float* __restrict__ gamma, const float* __restrict__ beta,
    int total4, float invN) {
  const int tid = threadIdx.x;
  const int c4 = tid & 31;
  float4 s = ((const float4*)ws)[c4];
  float4 q = ((const float4*)ws)[32 + c4];
  float4 g = ((const float4*)gamma)[c4];
  float4 b = ((const float4*)beta)[c4];
  float m0 = s.x * invN, m1 = s.y * invN, m2 = s.z * invN, m3 = s.w * invN;
  float sc0 = g.x * rsqrtf(q.x * invN - m0 * m0 + EPS);
  float sc1 = g.y * rsqrtf(q.y * invN - m1 * m1 + EPS);
  float sc2 = g.z * rsqrtf(q.z * invN - m2 * m2 + EPS);
  float sc3 = g.w * rsqrtf(q.w * invN - m3 * m3 + EPS);
  float sh0 = b.x - m0 * sc0, sh1 = b.y - m1 * sc1;
  float sh2 = b.z - m2 * sc2, sh3 = b.w - m3 * sc3;
  float4* o4 = (float4*)out;
  for (int idx = blockIdx.x * 256 + tid; idx < total4; idx += gridDim.x * 256) {
    float4 v = o4[idx];
    v.x = fmaxf(v.x * sc0 + sh0, 0.f);
    v.y = fmaxf(v.y * sc1 + sh1, 0.f);
    v.z = fmaxf(v.z * sc2 + sh2, 0.f);
    v.w = fmaxf(v.w * sc3 + sh3, 0.f);
    o4[idx] = v;
  }
}

// ===========================================================================
extern "C" void kernel_launch(void* const* d_in, const int* in_sizes, int n_in,
                              void* d_out, int out_size, void* d_ws, size_t ws_size,
                              hipStream_t stream) {
  const float* f1 = (const float*)d_in[0];
  const float* f2 = (const float*)d_in[1];
  const float* W = (const float*)d_in[2];
  const float* bias = (const float*)d_in[3];
  const float* gamma = (const float*)d_in[4];
  const float* beta = (const float*)d_in[5];
  const int* G = (const int*)d_in[6];
  const int* S = (const int*)d_in[7];
  const int N1 = in_sizes[0] / 64;
  const int N2 = in_sizes[1] / 64;
  const int N = N1 + N2;
  const int pm = in_sizes[6] / 26;
  float* out = (float*)d_out;
  float* ws = (float*)d_ws;

  const size_t AL = 255;
  const size_t offR = 1024;
  const size_t Rb = (size_t)N * 26 * 4;
  const size_t offF = (offR + Rb + AL) & ~AL;
  const size_t Fb = (size_t)(N + 1) * 64 * 2;
  const size_t offW = (offF + Fb + AL) & ~AL;
  const size_t Wbyt = (size_t)27 * 128 * 64 * 2;
  const size_t offM = (offW + Wbyt + AL) & ~AL;
  const size_t Mb = (size_t)26 * pm * 128 * 2;
  const size_t offO = (offM + Mb + AL) & ~AL;
  const size_t Ob = (size_t)N * 128 * 2;
  const bool full = ws_size >= offO + Ob;

  // round-2 fallback layout
  const size_t offM2 = (offR + Rb + AL) & ~AL;
  const bool fast2 = ws_size >= offM2 + Mb;

  (void)hipMemsetAsync(ws, 0, 256 * sizeof(float), stream);

  if (full) {
    int* R = (int*)((char*)d_ws + offR);
    unsigned short* fbuf = (unsigned short*)((char*)d_ws + offF);
    unsigned short* Wb = (unsigned short*)((char*)d_ws + offW);
    unsigned short* msgbuf = (unsigned short*)((char*)d_ws + offM);
    unsigned short* outb = (unsigned short*)((char*)d_ws + offO);

    (void)hipMemsetAsync(R, 0xFF, Rb, stream);
    to_bf16<<<((N + 1) * 8 + 255) / 256, 256, 0, stream>>>(f1, f2, fbuf, N1, N);
    wconv<<<(27 * 128 * 64) / 256, 256, 0, stream>>>(W, Wb);
    scatter_R<<<dim3((pm + 255) / 256, 26), 256, 0, stream>>>(S, R, N, pm);

    center_mfma<<<(N + 127) / 128, 256, 0, stream>>>(
        fbuf, Wb + (size_t)13 * 128 * 64, bias, outb, N);
    msg_mfma<<<dim3((pm + 127) / 128, 26), 256, 0, stream>>>(
        fbuf, Wb, G, msgbuf, N, pm);

    combine_b<<<4096, 256, 0, stream>>>(outb, R, msgbuf, ws, N);
    norm_b<<<2048, 256, 0, stream>>>(outb, out, ws, gamma, beta, N * 16,
                                     1.0f / N);
  } else if (fast2) {
    int* R = (int*)((char*)d_ws + offR);
    unsigned short* msgbuf = (unsigned short*)((char*)d_ws + offM2);
    (void)hipMemsetAsync(R, 0xFF, Rb, stream);
    center_gemm<<<(N + 127) / 128, 256, 0, stream>>>(
        f1, f2, W + (size_t)13 * 64 * 128, bias, out, N, N1);
    scatter_R<<<dim3((pm + 255) / 256, 26), 256, 0, stream>>>(S, R, N, pm);
    msg_gemm_buf<<<dim3((pm + 127) / 128, 26), 256, 0, stream>>>(
        f1, f2, W, G, S, msgbuf, N, N1, pm);
    combine_stats<<<1024, 256, 0, stream>>>(out, R, msgbuf, ws, N);
    norm_kernel<<<2048, 256, 0, stream>>>(out, ws, gamma, beta, N * 32,
                                          1.0f / N);
  } else {
    center_gemm<<<(N + 127) / 128, 256, 0, stream>>>(
        f1, f2, W + (size_t)13 * 64 * 128, bias, out, N, N1);
    msg_gemm<<<dim3((pm + 127) / 128, 26), 256, 0, stream>>>(
        f1, f2, W, G, S, out, N, N1, pm);
    stats_kernel<<<1024, 256, 0, stream>>>(out, ws, N * 32);
    norm_kernel<<<2048, 256, 0, stream>>>(out, ws, gamma, beta, N * 32,
                                          1.0f / N);
  }
}

// Round 6
// 331.809 us; speedup vs baseline: 1.3851x; 1.3851x over previous
//
#include <hip/hip_runtime.h>

#define EPS 1e-3f

typedef __attribute__((ext_vector_type(8))) short bf8_t;   // 8 bf16 (4 VGPRs)
typedef __attribute__((ext_vector_type(4))) float f32x4;   // MFMA acc

static __device__ __forceinline__ unsigned f2bf_pack(float a, float b) {
  union { float f; unsigned u; } ca, cb;
  ca.f = a; cb.f = b;
  unsigned ra = (ca.u + 0x7FFFu + ((ca.u >> 16) & 1u)) >> 16;
  unsigned rb = (cb.u + 0x7FFFu + ((cb.u >> 16) & 1u)) >> 16;
  return ra | (rb << 16);
}
static __device__ __forceinline__ unsigned short f2bf1(float x) {
  union { float f; unsigned u; } c; c.f = x;
  return (unsigned short)((c.u + 0x7FFFu + ((c.u >> 16) & 1u)) >> 16);
}
static __device__ __forceinline__ float bf2f(unsigned bits16) {
  union { unsigned u; float f; } c;
  c.u = bits16 << 16;
  return c.f;
}

// ===========================================================================
// FULL (MFMA + bf16) PATH
// ws layout: [0,32KB) padded stats (sum[c] @ c*16 floats, sumsq @ 4096+c*16)
//            then R | fbuf | Wb | msgbuf | outb
// ===========================================================================

// feats (f1|f2) fp32 -> fbuf bf16, (N+1) rows x 64, row N = zeros
__global__ __launch_bounds__(256) void to_bf16(
    const float* __restrict__ f1, const float* __restrict__ f2,
    unsigned short* __restrict__ fbuf, int N1, int N) {
  int idx = blockIdx.x * 256 + threadIdx.x;  // (N+1)*8 segs of 8 elems
  if (idx >= (N + 1) * 8) return;
  int row = idx >> 3, seg = idx & 7;
  uint4 o = make_uint4(0, 0, 0, 0);
  if (row < N) {
    const float* src = (row < N1) ? (f1 + (size_t)row * 64)
                                  : (f2 + (size_t)(row - N1) * 64);
    float4 v0 = *(const float4*)(src + seg * 8);
    float4 v1 = *(const float4*)(src + seg * 8 + 4);
    o.x = f2bf_pack(v0.x, v0.y); o.y = f2bf_pack(v0.z, v0.w);
    o.z = f2bf_pack(v1.x, v1.y); o.w = f2bf_pack(v1.z, v1.w);
  }
  *(uint4*)(fbuf + (size_t)idx * 8) = o;
}

// W[27][64][128] fp32 -> Wb[27][128][64] bf16 (transposed, k contiguous)
__global__ __launch_bounds__(256) void wconv(
    const float* __restrict__ W, unsigned short* __restrict__ Wb) {
  int idx = blockIdx.x * 256 + threadIdx.x;  // 27*128*64 = 221184 exact
  int k = idx & 63, n = (idx >> 6) & 127, t = idx >> 13;
  Wb[idx] = f2bf1(W[((size_t)t * 64 + k) * 128 + n]);
}

// inverse rulebook: R[s*26+i] = i*pm+p (msgbuf row). R pre-memset to -1.
__global__ __launch_bounds__(256) void scatter_R(
    const int* __restrict__ S, int* __restrict__ R, int N, int pm) {
  const int p = blockIdx.x * 256 + threadIdx.x;
  const int i = blockIdx.y;
  if (p >= pm) return;
  const int idx = i * pm + p;
  const int s = S[idx];
  if (s < N) R[(size_t)s * 26 + i] = idx;
}

// center tap: outb[n][col] = bf16( feats[n].W13[:,col] + bias[col] )
__global__ __launch_bounds__(256) void center_mfma(
    const unsigned short* __restrict__ fbuf,
    const unsigned short* __restrict__ Wb13,
    const float* __restrict__ bias,
    unsigned short* __restrict__ outb, int N) {
  __shared__ unsigned short A[128 * 64];  // [rt(8)][c(2)][lane(64)][8]
  const int tid = threadIdx.x;
  const int row0 = blockIdx.x * 128;

#pragma unroll
  for (int it = 0; it < 4; ++it) {
    int flat = it * 256 + tid;
    int r = flat >> 3, qs = flat & 7;
    int g = row0 + r; if (g >= N) g = N;  // row N is zeros
    uint4 v = *(const uint4*)(fbuf + (size_t)g * 64 + qs * 8);
    int rt = r >> 4, m = r & 15, c = qs >> 2, qq = qs & 3;
    *(uint4*)(A + ((rt * 2 + c) * 64 + qq * 16 + m) * 8) = v;
  }
  __syncthreads();

  const int wave = tid >> 6, lane = tid & 63;
  const int ncol = lane & 15, q2 = lane >> 4;
  bf8_t Bf[2][2];
  float bs[2];
#pragma unroll
  for (int ct = 0; ct < 2; ++ct) {
    int col = wave * 32 + ct * 16 + ncol;
    bs[ct] = bias[col];
#pragma unroll
    for (int c = 0; c < 2; ++c)
      Bf[ct][c] = *(const bf8_t*)(Wb13 + (size_t)col * 64 + c * 32 + q2 * 8);
  }
  f32x4 acc[8][2];
#pragma unroll
  for (int rt = 0; rt < 8; ++rt)
#pragma unroll
    for (int ct = 0; ct < 2; ++ct) acc[rt][ct] = (f32x4){0.f, 0.f, 0.f, 0.f};

#pragma unroll
  for (int rt = 0; rt < 8; ++rt) {
    bf8_t a0 = *(const bf8_t*)(A + ((rt * 2 + 0) * 64 + lane) * 8);
    bf8_t a1 = *(const bf8_t*)(A + ((rt * 2 + 1) * 64 + lane) * 8);
#pragma unroll
    for (int ct = 0; ct < 2; ++ct) {
      acc[rt][ct] = __builtin_amdgcn_mfma_f32_16x16x32_bf16(a0, Bf[ct][0], acc[rt][ct], 0, 0, 0);
      acc[rt][ct] = __builtin_amdgcn_mfma_f32_16x16x32_bf16(a1, Bf[ct][1], acc[rt][ct], 0, 0, 0);
    }
  }

#pragma unroll
  for (int rt = 0; rt < 8; ++rt)
#pragma unroll
    for (int ct = 0; ct < 2; ++ct) {
      int col = wave * 32 + ct * 16 + ncol;
#pragma unroll
      for (int e = 0; e < 4; ++e) {
        int row = row0 + rt * 16 + q2 * 4 + e;
        if (row < N)
          outb[(size_t)row * 128 + col] = f2bf1(acc[rt][ct][e] + bs[ct]);
      }
    }
}

// 26 neighbor taps: msgbuf[tap*pm+p] = bf16( feats[G[tap][p]] . W_k )
__global__ __launch_bounds__(256) void msg_mfma(
    const unsigned short* __restrict__ fbuf,
    const unsigned short* __restrict__ Wb,
    const int* __restrict__ G,
    unsigned short* __restrict__ msgbuf, int N, int pm) {
  const int tap = blockIdx.y;                 // tap index (0..25)
  const int ktap = tap + (tap >= 13 ? 1 : 0);
  const unsigned short* Wt = Wb + (size_t)ktap * 128 * 64;
  const int* Gi = G + (size_t)tap * pm;
  const int p0 = blockIdx.x * 128;
  if (Gi[p0] >= N) return;  // fully-padded tail block (padding G == N)

  __shared__ unsigned short A[128 * 64];
  __shared__ int g_lds[128];
  const int tid = threadIdx.x;
  if (tid < 128) {
    int p = p0 + tid;
    g_lds[tid] = (p < pm) ? Gi[p] : N;
  }
  __syncthreads();

#pragma unroll
  for (int it = 0; it < 4; ++it) {
    int flat = it * 256 + tid;
    int r = flat >> 3, qs = flat & 7;
    int g = g_lds[r];
    uint4 v = *(const uint4*)(fbuf + (size_t)g * 64 + qs * 8);
    int rt = r >> 4, m = r & 15, c = qs >> 2, qq = qs & 3;
    *(uint4*)(A + ((rt * 2 + c) * 64 + qq * 16 + m) * 8) = v;
  }
  __syncthreads();

  const int wave = tid >> 6, lane = tid & 63;
  const int ncol = lane & 15, q2 = lane >> 4;
  bf8_t Bf[2][2];
#pragma unroll
  for (int ct = 0; ct < 2; ++ct) {
    int col = wave * 32 + ct * 16 + ncol;
#pragma unroll
    for (int c = 0; c < 2; ++c)
      Bf[ct][c] = *(const bf8_t*)(Wt + (size_t)col * 64 + c * 32 + q2 * 8);
  }
  f32x4 acc[8][2];
#pragma unroll
  for (int rt = 0; rt < 8; ++rt)
#pragma unroll
    for (int ct = 0; ct < 2; ++ct) acc[rt][ct] = (f32x4){0.f, 0.f, 0.f, 0.f};

#pragma unroll
  for (int rt = 0; rt < 8; ++rt) {
    bf8_t a0 = *(const bf8_t*)(A + ((rt * 2 + 0) * 64 + lane) * 8);
    bf8_t a1 = *(const bf8_t*)(A + ((rt * 2 + 1) * 64 + lane) * 8);
#pragma unroll
    for (int ct = 0; ct < 2; ++ct) {
      acc[rt][ct] = __builtin_amdgcn_mfma_f32_16x16x32_bf16(a0, Bf[ct][0], acc[rt][ct], 0, 0, 0);
      acc[rt][ct] = __builtin_amdgcn_mfma_f32_16x16x32_bf16(a1, Bf[ct][1], acc[rt][ct], 0, 0, 0);
    }
  }

#pragma unroll
  for (int rt = 0; rt < 8; ++rt)
#pragma unroll
    for (int ct = 0; ct < 2; ++ct) {
      int col = wave * 32 + ct * 16 + ncol;
#pragma unroll
      for (int e = 0; e < 4; ++e) {
        int p = p0 + rt * 16 + q2 * 4 + e;
        if (p < pm)
          msgbuf[((size_t)tap * pm + p) * 128 + col] = f2bf1(acc[rt][ct][e]);
      }
    }
}

// combine: outb[j] += sum of its bf16 messages (via R); per-channel stats.
// Stats atomics padded: one 64B cache line per counter (no same-line serial).
__global__ __launch_bounds__(256) void combine_b(
    unsigned short* __restrict__ outb, const int* __restrict__ R,
    const unsigned short* __restrict__ msgbuf, float* __restrict__ ws,
    int N) {
  const int tid = threadIdx.x;
  const int grp = tid >> 5, l = tid & 31;
  const int base = tid & 32;
  float4 s = make_float4(0.f, 0.f, 0.f, 0.f);
  float4 q = make_float4(0.f, 0.f, 0.f, 0.f);

  for (int j = blockIdx.x * 8 + grp; j < N; j += gridDim.x * 8) {
    uint2 ov = ((const uint2*)(outb + (size_t)j * 128))[l];
    float4 v;
    v.x = bf2f(ov.x & 0xffffu); v.y = bf2f(ov.x >> 16);
    v.z = bf2f(ov.y & 0xffffu); v.w = bf2f(ov.y >> 16);
    int r = (l < 26) ? R[(size_t)j * 26 + l] : -1;
    unsigned long long bal = __ballot(r >= 0);
    unsigned mym = (unsigned)((bal >> base) & 0x3FFFFFFull);
    const bool any = (mym != 0);
    while (mym) {
      int b = __builtin_ctz(mym);
      mym &= mym - 1;
      int ptr = __shfl(r, base + b, 64);
      uint2 mv = ((const uint2*)(msgbuf + (size_t)ptr * 128))[l];
      v.x += bf2f(mv.x & 0xffffu); v.y += bf2f(mv.x >> 16);
      v.z += bf2f(mv.y & 0xffffu); v.w += bf2f(mv.y >> 16);
    }
    if (any) {
      uint2 pk;
      pk.x = f2bf_pack(v.x, v.y); pk.y = f2bf_pack(v.z, v.w);
      ((uint2*)(outb + (size_t)j * 128))[l] = pk;
    }
    s.x += v.x; s.y += v.y; s.z += v.z; s.w += v.w;
    q.x += v.x * v.x; q.y += v.y * v.y; q.z += v.z * v.z; q.w += v.w * v.w;
  }

  __shared__ float red[8 * 32 * 9];   // stride 9: coprime with 32 banks
  float* my = red + (grp * 32 + l) * 9;
  my[0] = s.x; my[1] = s.y; my[2] = s.z; my[3] = s.w;
  my[4] = q.x; my[5] = q.y; my[6] = q.z; my[7] = q.w;
  __syncthreads();
  {
    int c4 = tid & 31, jj = tid >> 5;
    float v = 0.f;
#pragma unroll
    for (int g = 0; g < 8; ++g) v += red[(g * 32 + c4) * 9 + jj];
    int col = c4 * 4 + (jj & 3);
    // sum[col] @ ws[col*16]; sumsq[col] @ ws[4096 + col*16]  (64B apart)
    unsafeAtomicAdd(&ws[(jj >> 2) * 4096 + col * 16], v);
  }
}

// normalize bf16 pre-norm buffer -> fp32 final out (reads padded stats)
__global__ __launch_bounds__(256) void norm_b(
    const unsigned short* __restrict__ outb, float* __restrict__ out,
    const float* __restrict__ ws, const float* __restrict__ gamma,
    const float* __restrict__ beta, int total8, float invN) {
  const int tid0 = blockIdx.x * 256 + threadIdx.x;
  const int c0 = (tid0 & 15) * 8;
  float sc[8], sh[8];
#pragma unroll
  for (int k = 0; k < 8; ++k) {
    float m = ws[(c0 + k) * 16] * invN;
    float var = ws[4096 + (c0 + k) * 16] * invN - m * m;
    sc[k] = gamma[c0 + k] * rsqrtf(var + EPS);
    sh[k] = beta[c0 + k] - m * sc[k];
  }
  for (int idx = tid0; idx < total8; idx += gridDim.x * 256) {
    uint4 v = *(const uint4*)(outb + (size_t)idx * 8);
    float f0 = bf2f(v.x & 0xffffu), f1 = bf2f(v.x >> 16);
    float f2 = bf2f(v.y & 0xffffu), f3 = bf2f(v.y >> 16);
    float f4 = bf2f(v.z & 0xffffu), f5 = bf2f(v.z >> 16);
    float f6 = bf2f(v.w & 0xffffu), f7 = bf2f(v.w >> 16);
    float4 o0, o1;
    o0.x = fmaxf(f0 * sc[0] + sh[0], 0.f);
    o0.y = fmaxf(f1 * sc[1] + sh[1], 0.f);
    o0.z = fmaxf(f2 * sc[2] + sh[2], 0.f);
    o0.w = fmaxf(f3 * sc[3] + sh[3], 0.f);
    o1.x = fmaxf(f4 * sc[4] + sh[4], 0.f);
    o1.y = fmaxf(f5 * sc[5] + sh[5], 0.f);
    o1.z = fmaxf(f6 * sc[6] + sh[6], 0.f);
    o1.w = fmaxf(f7 * sc[7] + sh[7], 0.f);
    *(float4*)(out + (size_t)idx * 8) = o0;
    *(float4*)(out + (size_t)idx * 8 + 4) = o1;
  }
}

// ===========================================================================
// FALLBACK PATHS (round-2 fp32 pipeline; round-1 atomic pipeline)
// (unpadded ws stats layout: sum @ ws[0..128), sumsq @ ws[128..256))
// ===========================================================================

__global__ __launch_bounds__(256) void center_gemm(
    const float* __restrict__ f1, const float* __restrict__ f2,
    const float* __restrict__ W, const float* __restrict__ bias,
    float* __restrict__ out, int N, int N1) {
  __shared__ float fLDS[128 * 65];
  __shared__ float wLDS[32 * 128];
  const int tid = threadIdx.x;
  const int tx = tid & 15, ty = tid >> 4;
  const int row0 = blockIdx.x * 128;

  for (int k = 0; k < 8; ++k) {
    int flat4 = tid + k * 256;
    int row = flat4 >> 4, c4 = flat4 & 15;
    int grow = row0 + row;
    float4 v = make_float4(0.f, 0.f, 0.f, 0.f);
    if (grow < N) {
      const float* src = (grow < N1) ? (f1 + (size_t)grow * 64)
                                     : (f2 + (size_t)(grow - N1) * 64);
      v = *(const float4*)(src + c4 * 4);
    }
    int l = row * 65 + c4 * 4;
    fLDS[l + 0] = v.x; fLDS[l + 1] = v.y; fLDS[l + 2] = v.z; fLDS[l + 3] = v.w;
  }
  float acc[8][8];
#pragma unroll
  for (int r = 0; r < 8; ++r)
#pragma unroll
    for (int j = 0; j < 8; ++j) acc[r][j] = 0.f;
  for (int kk = 0; kk < 64; kk += 32) {
    __syncthreads();
    for (int k = 0; k < 4; ++k) {
      int flat4 = tid + k * 256;
      int c = flat4 >> 5, col4 = flat4 & 31;
      float4 v = *(const float4*)(W + (size_t)(kk + c) * 128 + col4 * 4);
      *(float4*)(wLDS + c * 128 + col4 * 4) = v;
    }
    __syncthreads();
#pragma unroll 4
    for (int c = 0; c < 32; ++c) {
      float a[8];
#pragma unroll
      for (int r = 0; r < 8; ++r) a[r] = fLDS[(ty * 8 + r) * 65 + kk + c];
      float4 b0 = *(const float4*)(wLDS + c * 128 + tx * 8);
      float4 b1 = *(const float4*)(wLDS + c * 128 + tx * 8 + 4);
      float b[8] = {b0.x, b0.y, b0.z, b0.w, b1.x, b1.y, b1.z, b1.w};
#pragma unroll
      for (int r = 0; r < 8; ++r)
#pragma unroll
        for (int j = 0; j < 8; ++j) acc[r][j] += a[r] * b[j];
    }
  }
  float4 bi0 = *(const float4*)(bias + tx * 8);
  float4 bi1 = *(const float4*)(bias + tx * 8 + 4);
#pragma unroll
  for (int r = 0; r < 8; ++r) {
    int grow = row0 + ty * 8 + r;
    if (grow < N) {
      float4 o0 = make_float4(acc[r][0] + bi0.x, acc[r][1] + bi0.y,
                              acc[r][2] + bi0.z, acc[r][3] + bi0.w);
      float4 o1 = make_float4(acc[r][4] + bi1.x, acc[r][5] + bi1.y,
                              acc[r][6] + bi1.z, acc[r][7] + bi1.w);
      float* dst = out + (size_t)grow * 128 + tx * 8;
      *(float4*)dst = o0;
      *(float4*)(dst + 4) = o1;
    }
  }
}

__global__ __launch_bounds__(256) void msg_gemm_buf(
    const float* __restrict__ f1, const float* __restrict__ f2,
    const float* __restrict__ W27, const int* __restrict__ G,
    const int* __restrict__ S, unsigned short* __restrict__ msgbuf,
    int N, int N1, int pm) {
  const int i = blockIdx.y;
  const int ktap = i + (i >= 13 ? 1 : 0);
  const float* W = W27 + (size_t)ktap * 64 * 128;
  const int* Gi = G + (size_t)i * pm;
  const int* Si = S + (size_t)i * pm;
  const int p0 = blockIdx.x * 128;
  if (Si[p0] >= N) return;
  __shared__ float fLDS[128 * 65];
  __shared__ float wLDS[32 * 128];
  const int tid = threadIdx.x;
  const int tx = tid & 15, ty = tid >> 4;
  for (int k = 0; k < 8; ++k) {
    int flat4 = tid + k * 256;
    int row = flat4 >> 4, c4 = flat4 & 15;
    int p = p0 + row;
    float4 v = make_float4(0.f, 0.f, 0.f, 0.f);
    if (p < pm) {
      int g = Gi[p];
      if (g < N) {
        const float* src = (g < N1) ? (f1 + (size_t)g * 64)
                                    : (f2 + (size_t)(g - N1) * 64);
        v = *(const float4*)(src + c4 * 4);
      }
    }
    int l = row * 65 + c4 * 4;
    fLDS[l + 0] = v.x; fLDS[l + 1] = v.y; fLDS[l + 2] = v.z; fLDS[l + 3] = v.w;
  }
  float acc[8][8];
#pragma unroll
  for (int r = 0; r < 8; ++r)
#pragma unroll
    for (int j = 0; j < 8; ++j) acc[r][j] = 0.f;
  for (int kk = 0; kk < 64; kk += 32) {
    __syncthreads();
    for (int k = 0; k < 4; ++k) {
      int flat4 = tid + k * 256;
      int c = flat4 >> 5, col4 = flat4 & 31;
      float4 v = *(const float4*)(W + (size_t)(kk + c) * 128 + col4 * 4);
      *(float4*)(wLDS + c * 128 + col4 * 4) = v;
    }
    __syncthreads();
#pragma unroll 4
    for (int c = 0; c < 32; ++c) {
      float a[8];
#pragma unroll
      for (int r = 0; r < 8; ++r) a[r] = fLDS[(ty * 8 + r) * 65 + kk + c];
      float4 b0 = *(const float4*)(wLDS + c * 128 + tx * 8);
      float4 b1 = *(const float4*)(wLDS + c * 128 + tx * 8 + 4);
      float b[8] = {b0.x, b0.y, b0.z, b0.w, b1.x, b1.y, b1.z, b1.w};
#pragma unroll
      for (int r = 0; r < 8; ++r)
#pragma unroll
        for (int j = 0; j < 8; ++j) acc[r][j] += a[r] * b[j];
    }
  }
#pragma unroll
  for (int r = 0; r < 8; ++r) {
    int p = p0 + ty * 8 + r;
    if (p < pm) {
      uint4 pk;
      pk.x = f2bf_pack(acc[r][0], acc[r][1]);
      pk.y = f2bf_pack(acc[r][2], acc[r][3]);
      pk.z = f2bf_pack(acc[r][4], acc[r][5]);
      pk.w = f2bf_pack(acc[r][6], acc[r][7]);
      *(uint4*)(msgbuf + ((size_t)i * pm + p) * 128 + tx * 8) = pk;
    }
  }
}

__global__ __launch_bounds__(256) void msg_gemm(
    const float* __restrict__ f1, const float* __restrict__ f2,
    const float* __restrict__ W27, const int* __restrict__ G,
    const int* __restrict__ S, float* __restrict__ out,
    int N, int N1, int pm) {
  const int i = blockIdx.y;
  const int ktap = i + (i >= 13 ? 1 : 0);
  const float* W = W27 + (size_t)ktap * 64 * 128;
  const int* Gi = G + (size_t)i * pm;
  const int* Si = S + (size_t)i * pm;
  const int p0 = blockIdx.x * 128;
  if (Si[p0] >= N) return;
  __shared__ float fLDS[128 * 65];
  __shared__ float wLDS[32 * 128];
  const int tid = threadIdx.x;
  const int tx = tid & 15, ty = tid >> 4;
  for (int k = 0; k < 8; ++k) {
    int flat4 = tid + k * 256;
    int row = flat4 >> 4, c4 = flat4 & 15;
    int p = p0 + row;
    float4 v = make_float4(0.f, 0.f, 0.f, 0.f);
    if (p < pm) {
      int g = Gi[p];
      if (g < N) {
        const float* src = (g < N1) ? (f1 + (size_t)g * 64)
                                    : (f2 + (size_t)(g - N1) * 64);
        v = *(const float4*)(src + c4 * 4);
      }
    }
    int l = row * 65 + c4 * 4;
    fLDS[l + 0] = v.x; fLDS[l + 1] = v.y; fLDS[l + 2] = v.z; fLDS[l + 3] = v.w;
  }
  float acc[8][8];
#pragma unroll
  for (int r = 0; r < 8; ++r)
#pragma unroll
    for (int j = 0; j < 8; ++j) acc[r][j] = 0.f;
  for (int kk = 0; kk < 64; kk += 32) {
    __syncthreads();
    for (int k = 0; k < 4; ++k) {
      int flat4 = tid + k * 256;
      int c = flat4 >> 5, col4 = flat4 & 31;
      float4 v = *(const float4*)(W + (size_t)(kk + c) * 128 + col4 * 4);
      *(float4*)(wLDS + c * 128 + col4 * 4) = v;
    }
    __syncthreads();
#pragma unroll 4
    for (int c = 0; c < 32; ++c) {
      float a[8];
#pragma unroll
      for (int r = 0; r < 8; ++r) a[r] = fLDS[(ty * 8 + r) * 65 + kk + c];
      float4 b0 = *(const float4*)(wLDS + c * 128 + tx * 8);
      float4 b1 = *(const float4*)(wLDS + c * 128 + tx * 8 + 4);
      float b[8] = {b0.x, b0.y, b0.z, b0.w, b1.x, b1.y, b1.z, b1.w};
#pragma unroll
      for (int r = 0; r < 8; ++r)
#pragma unroll
        for (int j = 0; j < 8; ++j) acc[r][j] += a[r] * b[j];
    }
  }
#pragma unroll
  for (int r = 0; r < 8; ++r) {
    int p = p0 + ty * 8 + r;
    if (p < pm) {
      int s = Si[p];
      if (s < N) {
        float* dst = out + (size_t)s * 128 + tx * 8;
#pragma unroll
        for (int j = 0; j < 8; ++j) unsafeAtomicAdd(dst + j, acc[r][j]);
      }
    }
  }
}

__global__ __launch_bounds__(256) void combine_stats(
    float* __restrict__ out, const int* __restrict__ R,
    const unsigned short* __restrict__ msgbuf, float* __restrict__ ws,
    int N) {
  const int tid = threadIdx.x;
  const int grp = tid >> 5, l = tid & 31;
  const int base = tid & 32;
  float4 s = make_float4(0.f, 0.f, 0.f, 0.f);
  float4 q = make_float4(0.f, 0.f, 0.f, 0.f);
  for (int j = blockIdx.x * 8 + grp; j < N; j += gridDim.x * 8) {
    float4 v = ((const float4*)(out + (size_t)j * 128))[l];
    int r = (l < 26) ? R[(size_t)j * 26 + l] : -1;
    unsigned long long bal = __ballot(r >= 0);
    unsigned mym = (unsigned)((bal >> base) & 0x3FFFFFFull);
    const bool any = (mym != 0);
    while (mym) {
      int b = __builtin_ctz(mym);
      mym &= mym - 1;
      int ptr = __shfl(r, base + b, 64);
      uint2 mv = ((const uint2*)(msgbuf + (size_t)ptr * 128))[l];
      v.x += bf2f(mv.x & 0xffffu);
      v.y += bf2f(mv.x >> 16);
      v.z += bf2f(mv.y & 0xffffu);
      v.w += bf2f(mv.y >> 16);
    }
    if (any) ((float4*)(out + (size_t)j * 128))[l] = v;
    s.x += v.x; s.y += v.y; s.z += v.z; s.w += v.w;
    q.x += v.x * v.x; q.y += v.y * v.y; q.z += v.z * v.z; q.w += v.w * v.w;
  }
  __shared__ float red[8 * 32 * 8];
  float* my = red + (grp * 32 + l) * 8;
  my[0] = s.x; my[1] = s.y; my[2] = s.z; my[3] = s.w;
  my[4] = q.x; my[5] = q.y; my[6] = q.z; my[7] = q.w;
  __syncthreads();
  {
    int c4 = tid & 31, j = tid >> 5;
    float v = 0.f;
#pragma unroll
    for (int g = 0; g < 8; ++g) v += red[(g * 32 + c4) * 8 + j];
    int col = c4 * 4 + (j & 3);
    unsafeAtomicAdd(&ws[col + (j >> 2) * 128], v);
  }
}

__global__ __launch_bounds__(256) void stats_kernel(
    const float* __restrict__ out, float* __restrict__ ws, int total4) {
  const int tid = threadIdx.x;
  float4 s = make_float4(0.f, 0.f, 0.f, 0.f);
  float4 q = make_float4(0.f, 0.f, 0.f, 0.f);
  const float4* o4 = (const float4*)out;
  for (int idx = blockIdx.x * 256 + tid; idx < total4; idx += gridDim.x * 256) {
    float4 v = o4[idx];
    s.x += v.x; s.y += v.y; s.z += v.z; s.w += v.w;
    q.x += v.x * v.x; q.y += v.y * v.y; q.z += v.z * v.z; q.w += v.w * v.w;
  }
  __shared__ float red[8 * 32 * 8];
  const int col4 = tid & 31, grpq = tid >> 5;
  float* my = red + (grpq * 32 + col4) * 8;
  my[0] = s.x; my[1] = s.y; my[2] = s.z; my[3] = s.w;
  my[4] = q.x; my[5] = q.y; my[6] = q.z; my[7] = q.w;
  __syncthreads();
  {
    int c4 = tid & 31, j = tid >> 5;
    float v = 0.f;
#pragma unroll
    for (int g = 0; g < 8; ++g) v += red[(g * 32 + c4) * 8 + j];
    int col = c4 * 4 + (j & 3);
    unsafeAtomicAdd(&ws[col + (j >> 2) * 128], v);
  }
}

__global__ __launch_bounds__(256) void norm_kernel(
    float* __restrict__ out, const float* __restrict__ ws,
    const float* __restrict__ gamma, const float* __restrict__ beta,
    int total4, float invN) {
  const int tid = threadIdx.x;
  const int c4 = tid & 31;
  float4 s = ((const float4*)ws)[c4];
  float4 q = ((const float4*)ws)[32 + c4];
  float4 g = ((const float4*)gamma)[c4];
  float4 b = ((const float4*)beta)[c4];
  float m0 = s.x * invN, m1 = s.y * invN, m2 = s.z * invN, m3 = s.w * invN;
  float sc0 = g.x * rsqrtf(q.x * invN - m0 * m0 + EPS);
  float sc1 = g.y * rsqrtf(q.y * invN - m1 * m1 + EPS);
  float sc2 = g.z * rsqrtf(q.z * invN - m2 * m2 + EPS);
  float sc3 = g.w * rsqrtf(q.w * invN - m3 * m3 + EPS);
  float sh0 = b.x - m0 * sc0, sh1 = b.y - m1 * sc1;
  float sh2 = b.z - m2 * sc2, sh3 = b.w - m3 * sc3;
  float4* o4 = (float4*)out;
  for (int idx = blockIdx.x * 256 + tid; idx < total4; idx += gridDim.x * 256) {
    float4 v = o4[idx];
    v.x = fmaxf(v.x * sc0 + sh0, 0.f);
    v.y = fmaxf(v.y * sc1 + sh1, 0.f);
    v.z = fmaxf(v.z * sc2 + sh2, 0.f);
    v.w = fmaxf(v.w * sc3 + sh3, 0.f);
    o4[idx] = v;
  }
}

// ===========================================================================
extern "C" void kernel_launch(void* const* d_in, const int* in_sizes, int n_in,
                              void* d_out, int out_size, void* d_ws, size_t ws_size,
                              hipStream_t stream) {
  const float* f1 = (const float*)d_in[0];
  const float* f2 = (const float*)d_in[1];
  const float* W = (const float*)d_in[2];
  const float* bias = (const float*)d_in[3];
  const float* gamma = (const float*)d_in[4];
  const float* beta = (const float*)d_in[5];
  const int* G = (const int*)d_in[6];
  const int* S = (const int*)d_in[7];
  const int N1 = in_sizes[0] / 64;
  const int N2 = in_sizes[1] / 64;
  const int N = N1 + N2;
  const int pm = in_sizes[6] / 26;
  float* out = (float*)d_out;
  float* ws = (float*)d_ws;

  const size_t AL = 255;
  // full path layout (padded stats: 32 KB)
  const size_t offR = 32768;
  const size_t Rb = (size_t)N * 26 * 4;
  const size_t offF = (offR + Rb + AL) & ~AL;
  const size_t Fb = (size_t)(N + 1) * 64 * 2;
  const size_t offW = (offF + Fb + AL) & ~AL;
  const size_t Wbyt = (size_t)27 * 128 * 64 * 2;
  const size_t offM = (offW + Wbyt + AL) & ~AL;
  const size_t Mb = (size_t)26 * pm * 128 * 2;
  const size_t offO = (offM + Mb + AL) & ~AL;
  const size_t Ob = (size_t)N * 128 * 2;
  const bool full = ws_size >= offO + Ob;

  // round-2 fallback layout (unpadded stats: 1 KB)
  const size_t offR2 = 1024;
  const size_t offM2 = (offR2 + Rb + AL) & ~AL;
  const bool fast2 = ws_size >= offM2 + Mb;

  if (full) {
    int* R = (int*)((char*)d_ws + offR);
    unsigned short* fbuf = (unsigned short*)((char*)d_ws + offF);
    unsigned short* Wb = (unsigned short*)((char*)d_ws + offW);
    unsigned short* msgbuf = (unsigned short*)((char*)d_ws + offM);
    unsigned short* outb = (unsigned short*)((char*)d_ws + offO);

    (void)hipMemsetAsync(ws, 0, 32768, stream);
    (void)hipMemsetAsync(R, 0xFF, Rb, stream);
    to_bf16<<<((N + 1) * 8 + 255) / 256, 256, 0, stream>>>(f1, f2, fbuf, N1, N);
    wconv<<<(27 * 128 * 64) / 256, 256, 0, stream>>>(W, Wb);
    scatter_R<<<dim3((pm + 255) / 256, 26), 256, 0, stream>>>(S, R, N, pm);

    center_mfma<<<(N + 127) / 128, 256, 0, stream>>>(
        fbuf, Wb + (size_t)13 * 128 * 64, bias, outb, N);
    msg_mfma<<<dim3((pm + 127) / 128, 26), 256, 0, stream>>>(
        fbuf, Wb, G, msgbuf, N, pm);

    combine_b<<<2048, 256, 0, stream>>>(outb, R, msgbuf, ws, N);
    norm_b<<<2048, 256, 0, stream>>>(outb, out, ws, gamma, beta, N * 16,
                                     1.0f / N);
  } else if (fast2) {
    int* R = (int*)((char*)d_ws + offR2);
    unsigned short* msgbuf = (unsigned short*)((char*)d_ws + offM2);
    (void)hipMemsetAsync(ws, 0, 256 * sizeof(float), stream);
    (void)hipMemsetAsync(R, 0xFF, Rb, stream);
    center_gemm<<<(N + 127) / 128, 256, 0, stream>>>(
        f1, f2, W + (size_t)13 * 64 * 128, bias, out, N, N1);
    scatter_R<<<dim3((pm + 255) / 256, 26), 256, 0, stream>>>(S, R, N, pm);
    msg_gemm_buf<<<dim3((pm + 127) / 128, 26), 256, 0, stream>>>(
        f1, f2, W, G, S, msgbuf, N, N1, pm);
    combine_stats<<<1024, 256, 0, stream>>>(out, R, msgbuf, ws, N);
    norm_kernel<<<2048, 256, 0, stream>>>(out, ws, gamma, beta, N * 32,
                                          1.0f / N);
  } else {
    (void)hipMemsetAsync(ws, 0, 256 * sizeof(float), stream);
    center_gemm<<<(N + 127) / 128, 256, 0, stream>>>(
        f1, f2, W + (size_t)13 * 64 * 128, bias, out, N, N1);
    msg_gemm<<<dim3((pm + 127) / 128, 26), 256, 0, stream>>>(
        f1, f2, W, G, S, out, N, N1, pm);
    stats_kernel<<<1024, 256, 0, stream>>>(out, ws, N * 32);
    norm_kernel<<<2048, 256, 0, stream>>>(out, ws, gamma, beta, N * 32,
                                          1.0f / N);
  }
}